// Round 4
// baseline (1743.759 us; speedup 1.0000x reference)
//
#include <hip/hip_runtime.h>

typedef unsigned short u16;
typedef float f32x4 __attribute__((ext_vector_type(4)));
typedef u16 u16x8 __attribute__((ext_vector_type(8)));
typedef u16 u16x4 __attribute__((ext_vector_type(4)));
typedef __bf16 bf16x8 __attribute__((ext_vector_type(8)));

#define M_ROWS 18464
#define NSEQ   577
#define NPAD   608
#define QMAXF  255.0f

// ---------------- workspace layout (bytes), peak ~160 MiB ----------------
// region1 [0, 50.4MB): ix+Bh+Bl (die after gemm_qk) -> ik (dies after attn) -> io
// region2 [50.4, 126MB): vbuf fp32 (dies after quant_v) -> kbuf fp32 (dies after
//                        quant_k) -> iq (dies after attn)
// region3 [126, 165.9MB): ivT
// qbuf fp32 lives in d_out (dead after quant_q); attn out fp32 also in d_out.
static constexpr size_t OFF_IX  = 0;                    // 37,814,272
static constexpr size_t OFF_BH  = 37814272;             //  6,291,456
static constexpr size_t OFF_BL  = 44105728;             //  6,291,456 (end 50,397,184)
static constexpr size_t OFF_IK  = 0;                    // 39,845,888
static constexpr size_t OFF_IO  = 0;                    // 37,814,272
static constexpr size_t OFF_F32 = 50397184;             // 75,628,544 (vbuf, then kbuf)
static constexpr size_t OFF_IQ  = 50397184;             // 39,845,888
static constexpr size_t OFF_IVT = 126025728;            // 39,845,888
static constexpr size_t OFF_IPW = 165871616;            //  2,097,152
static constexpr size_t OFF_PAR = 167968768;            // ~33 KB params
static constexpr size_t WS_NEED = 168100000;

// param element indices (within par area)
#define P_XMN   0      /* 1024 */
#define P_XMX   1024   /* 1024 */
#define P_SX    2048   /* 1024 */
#define P_ZPX   3072   /* 1024 */
#define P_SWQ   4096   /* 3072 */
#define P_SPW   7168   /* 1024 */
#define P_QKVMM 8192   /* 6: q mn/mx, k mn/mx, v mn/mx */
#define P_OUTMM 8198   /* 2 */
#define P_PQ    8200   /* 7: sq,zpq,sk,zpk,sv,zpv,lscale */
#define P_PO    8208   /* 2: so,zpo */

// ---------------- small helpers ----------------
__device__ __forceinline__ u16 f2bf(float f){
  unsigned u = __float_as_uint(f);
  unsigned r = u + 0x7fffu + ((u >> 16) & 1u);
  return (u16)(r >> 16);
}
__device__ __forceinline__ float bf2f(u16 h){ return __uint_as_float(((unsigned)h) << 16); }

__device__ __forceinline__ unsigned ford(float f){
  unsigned u = __float_as_uint(f);
  return (u & 0x80000000u) ? ~u : (u | 0x80000000u);
}
__device__ __forceinline__ float unford(unsigned u){
  return (u & 0x80000000u) ? __uint_as_float(u & 0x7fffffffu) : __uint_as_float(~u);
}

__device__ __forceinline__ f32x4 mfma16(u16x8 a, u16x8 b, f32x4 c){
  return __builtin_amdgcn_mfma_f32_16x16x32_bf16(
      __builtin_bit_cast(bf16x8, a), __builtin_bit_cast(bf16x8, b), c, 0, 0, 0);
}

__device__ __forceinline__ void gload_lds16(const void* g, void* l){
  __builtin_amdgcn_global_load_lds((const __attribute__((address_space(1))) unsigned int*)g,
                                   (__attribute__((address_space(3))) unsigned int*)l,
                                   16, 0, 0);
}

// grouped + XCD-bijective tile mapping (requires nwg%8==0, MT%GM==0)
__device__ __forceinline__ void tilemap(int id, int nwg, int NT, int GM, int& mt, int& nt){
  int q = nwg >> 3;
  int swz = (id & 7) * q + (id >> 3);
  int gsz = GM * NT;
  int g = swz / gsz, r = swz % gsz;
  mt = g * GM + (r % GM);
  nt = r / GM;
}

// ---------------- kernels ----------------
__global__ void k_init(unsigned* par){
  int t = threadIdx.x;
  for (int i = t; i < 1024; i += 256){ par[P_XMN + i] = 0xFFFFFFFFu; par[P_XMX + i] = 0u; }
  if (t < 6) par[P_QKVMM + t] = (t & 1) ? 0u : 0xFFFFFFFFu;
  if (t < 2) par[P_OUTMM + t] = (t & 1) ? 0u : 0xFFFFFFFFu;
}

__global__ void k_minmax_x(const float* __restrict__ x, unsigned* par){
  int t = threadIdx.x;
  int r0 = blockIdx.x * 145;
  int r1 = min(r0 + 145, M_ROWS);
  float mn[4], mx[4];
#pragma unroll
  for (int e = 0; e < 4; e++){ mn[e] = 1e38f; mx[e] = -1e38f; }
  for (int r = r0; r < r1; r++){
    f32x4 v = *(const f32x4*)&x[(size_t)r * 1024 + t * 4];
#pragma unroll
    for (int e = 0; e < 4; e++){ mn[e] = fminf(mn[e], v[e]); mx[e] = fmaxf(mx[e], v[e]); }
  }
#pragma unroll
  for (int e = 0; e < 4; e++){
    atomicMin(&par[P_XMN + t * 4 + e], ford(mn[e]));
    atomicMax(&par[P_XMX + t * 4 + e], ford(mx[e]));
  }
}

__global__ void k_params_x(unsigned* paru){
  float* par = (float*)paru;
  int c = blockIdx.x * 256 + threadIdx.x;
  if (c < 1024){
    float mn = unford(paru[P_XMN + c]);
    float mx = unford(paru[P_XMX + c]);
    mn = fminf(mn, 0.f); mx = fmaxf(mx, 0.f);
    float s = fmaxf((mx - mn) / QMAXF, 1e-8f);
    par[P_SX + c] = s;
    par[P_ZPX + c] = rintf(-mn / s);
  }
}

__global__ void k_quant_x(const float* __restrict__ x, const float* __restrict__ par, u16* __restrict__ ix){
  const int total = M_ROWS * 1024 / 4;
  for (int i = blockIdx.x * blockDim.x + threadIdx.x; i < total; i += gridDim.x * blockDim.x){
    f32x4 v  = *(const f32x4*)&x[(size_t)i * 4];
    int c = (i * 4) & 1023;
    f32x4 s  = *(const f32x4*)&par[P_SX + c];
    f32x4 zp = *(const f32x4*)&par[P_ZPX + c];
    u16x4 o;
#pragma unroll
    for (int e = 0; e < 4; e++){
      float q = fminf(fmaxf(rintf(v[e] / s[e]) + zp[e], 0.f), QMAXF);
      o[e] = f2bf(q - zp[e]);
    }
    *(u16x4*)&ix[(size_t)i * 4] = o;
  }
}

// per-out-channel weight quant for qkv_w; Bh/Bl = bf16 split of sx_c * (qw - zpw)
__global__ void k_quant_wqkv(const float* __restrict__ w, const float* __restrict__ par,
                             float* __restrict__ swq, u16* __restrict__ Bh, u16* __restrict__ Bl){
  int lane = threadIdx.x & 63, wv = threadIdx.x >> 6;
  int row = blockIdx.x * 4 + wv;
  const float* wr = w + (size_t)row * 1024;
  f32x4 v[4];
  float mn = 1e38f, mx = -1e38f;
#pragma unroll
  for (int j = 0; j < 4; j++){
    v[j] = *(const f32x4*)&wr[j * 256 + lane * 4];
#pragma unroll
    for (int e = 0; e < 4; e++){ mn = fminf(mn, v[j][e]); mx = fmaxf(mx, v[j][e]); }
  }
#pragma unroll
  for (int m = 1; m < 64; m <<= 1){ mn = fminf(mn, __shfl_xor(mn, m)); mx = fmaxf(mx, __shfl_xor(mx, m)); }
  mn = fminf(mn, 0.f); mx = fmaxf(mx, 0.f);
  float s = fmaxf((mx - mn) / QMAXF, 1e-8f);
  float zp = rintf(-mn / s);
  if (lane == 0) swq[row] = s;
#pragma unroll
  for (int j = 0; j < 4; j++){
    int c = j * 256 + lane * 4;
    f32x4 sx = *(const f32x4*)&par[P_SX + c];
    u16x4 oh, ol;
#pragma unroll
    for (int e = 0; e < 4; e++){
      float q = fminf(fmaxf(rintf(v[j][e] / s) + zp, 0.f), QMAXF);
      float bp = sx[e] * (q - zp);
      u16 hh = f2bf(bp);
      oh[e] = hh;
      ol[e] = f2bf(bp - bf2f(hh));
    }
    *(u16x4*)&Bh[(size_t)row * 1024 + c] = oh;
    *(u16x4*)&Bl[(size_t)row * 1024 + c] = ol;
  }
}

// proj weight: exact int bf16, scale factored to epilogue
__global__ void k_quant_wproj(const float* __restrict__ w, float* __restrict__ spw, u16* __restrict__ ipw){
  int lane = threadIdx.x & 63, wv = threadIdx.x >> 6;
  int row = blockIdx.x * 4 + wv;
  const float* wr = w + (size_t)row * 1024;
  f32x4 v[4];
  float mn = 1e38f, mx = -1e38f;
#pragma unroll
  for (int j = 0; j < 4; j++){
    v[j] = *(const f32x4*)&wr[j * 256 + lane * 4];
#pragma unroll
    for (int e = 0; e < 4; e++){ mn = fminf(mn, v[j][e]); mx = fmaxf(mx, v[j][e]); }
  }
#pragma unroll
  for (int m = 1; m < 64; m <<= 1){ mn = fminf(mn, __shfl_xor(mn, m)); mx = fmaxf(mx, __shfl_xor(mx, m)); }
  mn = fminf(mn, 0.f); mx = fmaxf(mx, 0.f);
  float s = fmaxf((mx - mn) / QMAXF, 1e-8f);
  float zp = rintf(-mn / s);
  if (lane == 0) spw[row] = s;
#pragma unroll
  for (int j = 0; j < 4; j++){
    int c = j * 256 + lane * 4;
    u16x4 o;
#pragma unroll
    for (int e = 0; e < 4; e++){
      float q = fminf(fmaxf(rintf(v[j][e] / s) + zp, 0.f), QMAXF);
      o[e] = f2bf(q - zp);
    }
    *(u16x4*)&ipw[(size_t)row * 1024 + c] = o;
  }
}

// C[:, bcol_off : bcol_off+NT*128] = ix @ (Bh+Bl)^T * swq + bias; per-seg minmax.
// Local col cl<1024 -> dst0[row*1024+cl], else dst1[row*1024+cl-1024].
__global__ __launch_bounds__(256) void k_gemm_qkvpart(const u16* __restrict__ A,
    const u16* __restrict__ Bh, const u16* __restrict__ Bl, const float* __restrict__ swq,
    const float* __restrict__ bias, int bcol_off, int NT, float* dst0, float* dst1,
    int seg0, unsigned* paru){
  __shared__ u16 As[128 * 32], Bhs[128 * 32], Bls[128 * 32];
  int tid = threadIdx.x, lane = tid & 63, w = tid >> 6;
  int mt, nt; tilemap(blockIdx.x, gridDim.x, NT, 29, mt, nt);
  int m0 = mt * 128, n0 = nt * 128;
  int wr = (w >> 1) * 64, wc = (w & 1) * 64;
  f32x4 zero = {0.f, 0.f, 0.f, 0.f};
  f32x4 acc[4][4];
#pragma unroll
  for (int m = 0; m < 4; m++)
#pragma unroll
    for (int n = 0; n < 4; n++) acc[m][n] = zero;
  int kc = (lane & 3) * 8;
  for (int kt = 0; kt < 1024; kt += 32){
    __syncthreads();
#pragma unroll
    for (int i = 0; i < 2; i++){
      int ci = w * 2 + i;
      int r = ci * 16 + (lane >> 2);
      int gra = min(m0 + r, M_ROWS - 1);
      gload_lds16(&A[(size_t)gra * 1024 + kt + kc], &As[ci * 512]);
      size_t grb = (size_t)(bcol_off + n0 + r) * 1024 + kt + kc;
      gload_lds16(&Bh[grb], &Bhs[ci * 512]);
      gload_lds16(&Bl[grb], &Bls[ci * 512]);
    }
    __syncthreads();
    u16x8 af[4];
#pragma unroll
    for (int m = 0; m < 4; m++)
      af[m] = *(const u16x8*)&As[(wr + m * 16 + (lane & 15)) * 32 + (lane >> 4) * 8];
#pragma unroll
    for (int n = 0; n < 4; n++){
      u16x8 bh = *(const u16x8*)&Bhs[(wc + n * 16 + (lane & 15)) * 32 + (lane >> 4) * 8];
      u16x8 bl = *(const u16x8*)&Bls[(wc + n * 16 + (lane & 15)) * 32 + (lane >> 4) * 8];
#pragma unroll
      for (int m = 0; m < 4; m++){
        acc[m][n] = mfma16(af[m], bh, acc[m][n]);
        acc[m][n] = mfma16(af[m], bl, acc[m][n]);
      }
    }
  }
  float lmn = 1e38f, lmx = -1e38f;
#pragma unroll
  for (int n = 0; n < 4; n++){
    int cl = n0 + wc + n * 16 + (lane & 15);
    float sw = swq[bcol_off + cl], bv = bias[bcol_off + cl];
    float* dst = (cl < 1024) ? dst0 : dst1;
    int cs = cl & 1023;
#pragma unroll
    for (int m = 0; m < 4; m++){
      int rb = m0 + wr + m * 16 + (lane >> 4) * 4;
#pragma unroll
      for (int j = 0; j < 4; j++){
        int row = rb + j;
        if (row < M_ROWS){
          float vv = acc[m][n][j] * sw + bv;
          dst[(size_t)row * 1024 + cs] = vv;
          lmn = fminf(lmn, vv); lmx = fmaxf(lmx, vv);
        }
      }
    }
  }
  int seg = seg0 + (n0 >> 10);
#pragma unroll
  for (int m = 32; m; m >>= 1){ lmn = fminf(lmn, __shfl_xor(lmn, m)); lmx = fmaxf(lmx, __shfl_xor(lmx, m)); }
  if (lane == 0){
    atomicMin(&paru[P_QKVMM + seg * 2], ford(lmn));
    atomicMax(&paru[P_QKVMM + seg * 2 + 1], ford(lmx));
  }
}

__global__ void k_params_v(unsigned* paru){
  if (threadIdx.x == 0){
    float* par = (float*)paru;
    float mn = unford(paru[P_QKVMM + 4]);
    float mx = unford(paru[P_QKVMM + 5]);
    mn = fminf(mn, 0.f); mx = fmaxf(mx, 0.f);
    float s = fmaxf((mx - mn) / QMAXF, 1e-8f);
    par[P_PQ + 4] = s;
    par[P_PQ + 5] = rintf(-mn / s);
  }
}

__global__ void k_params_qk(unsigned* paru){
  if (threadIdx.x == 0){
    float* par = (float*)paru;
    float sv[2];
    for (int t = 0; t < 2; t++){
      float mn = unford(paru[P_QKVMM + t * 2]);
      float mx = unford(paru[P_QKVMM + t * 2 + 1]);
      mn = fminf(mn, 0.f); mx = fmaxf(mx, 0.f);
      float s = fmaxf((mx - mn) / QMAXF, 1e-8f);
      sv[t] = s;
      par[P_PQ + t * 2] = s;
      par[P_PQ + t * 2 + 1] = rintf(-mn / s);
    }
    par[P_PQ + 6] = sv[0] * sv[1] * 0.125f;
  }
}

// quantize v (per-tensor) + transpose head-block to [64][NPAD]
__global__ void k_quant_v(const float* __restrict__ vbuf, const float* __restrict__ par,
                          u16* __restrict__ ivT){
  int bh = blockIdx.x, b = bh >> 4, h = bh & 15;
  int tid = threadIdx.x;
  __shared__ unsigned vtu[64][37];
  float s = par[P_PQ + 4], zp = par[P_PQ + 5];
  const float* vsrc = vbuf + (size_t)b * 577 * 1024 + h * 64;
  u16* vdst = ivT + (size_t)bh * 64 * NPAD;
  for (int c0 = 0; c0 < 10; c0++){
    int n0 = c0 * 64;
    __syncthreads();
    for (int idx = tid; idx < 64 * 32; idx += 256){
      int d = idx & 63, p = idx >> 6;
      int n1 = n0 + 2 * p, n2 = n1 + 1;
      float v1 = 0.f, v2 = 0.f;
      if (n1 < NSEQ){
        float xx = vsrc[(size_t)n1 * 1024 + d];
        float q = fminf(fmaxf(rintf(xx / s) + zp, 0.f), QMAXF);
        v1 = q - zp;
      }
      if (n2 < NSEQ){
        float xx = vsrc[(size_t)n2 * 1024 + d];
        float q = fminf(fmaxf(rintf(xx / s) + zp, 0.f), QMAXF);
        v2 = q - zp;
      }
      vtu[d][p] = (unsigned)f2bf(v1) | ((unsigned)f2bf(v2) << 16);
    }
    __syncthreads();
    for (int idx = tid; idx < 64 * 32; idx += 256){
      int p = idx & 31, d = idx >> 5;
      int n = n0 + 2 * p;
      if (n < NPAD) *(unsigned*)&vdst[(size_t)d * NPAD + n] = vtu[d][p];
    }
  }
}

// quantize q or k (per-tensor) into [bh][NPAD][64] int-bf16
__global__ void k_quant_nd(const float* __restrict__ buf, const float* __restrict__ par,
                           int pidx, u16* __restrict__ dst){
  int bh = blockIdx.x, b = bh >> 4, h = bh & 15;
  int tid = threadIdx.x;
  float s = par[P_PQ + pidx], zp = par[P_PQ + pidx + 1];
  u16* d0p = dst + (size_t)bh * NPAD * 64;
  for (int idx = tid; idx < NPAD * 16; idx += 256){
    int n = idx >> 4, d0 = (idx & 15) * 4;
    u16x4 o = {0, 0, 0, 0};
    if (n < NSEQ){
      f32x4 v = *(const f32x4*)&buf[((size_t)(b * 577 + n)) * 1024 + h * 64 + d0];
#pragma unroll
      for (int e = 0; e < 4; e++){
        float q = fminf(fmaxf(rintf(v[e] / s) + zp, 0.f), QMAXF);
        o[e] = f2bf(q - zp);
      }
    }
    *(u16x4*)&d0p[n * 64 + d0] = o;
  }
}

__global__ __launch_bounds__(128) void k_attn(const u16* __restrict__ iq, const u16* __restrict__ ik,
    const u16* __restrict__ ivT, const float* __restrict__ par, float* __restrict__ out, unsigned* paru){
  __shared__ float S[32][612];
  __shared__ float rsum[32];
  int tile = blockIdx.x;
  int xcd = tile & 7, slot = tile >> 3;
  int bh = (slot / 19) * 8 + xcd, qt = slot % 19;
  int b = bh >> 4, h = bh & 15;
  int q0 = qt * 32;
  int tid = threadIdx.x, lane = tid & 63, w = tid >> 6;
  int r0 = w * 16;
  const u16* iqp = iq + (size_t)bh * NPAD * 64;
  const u16* ikp = ik + (size_t)bh * NPAD * 64;
  const u16* ivp = ivT + (size_t)bh * 64 * NPAD;
  float lscale = par[P_PQ + 6];
  u16x8 qf[2];
#pragma unroll
  for (int ks = 0; ks < 2; ks++)
    qf[ks] = *(const u16x8*)&iqp[(size_t)(q0 + r0 + (lane & 15)) * 64 + ks * 32 + (lane >> 4) * 8];
  f32x4 zero = {0.f, 0.f, 0.f, 0.f};
  for (int j = 0; j < 38; j++){
    f32x4 acc = zero;
#pragma unroll
    for (int ks = 0; ks < 2; ks++){
      u16x8 kf = *(const u16x8*)&ikp[(size_t)(j * 16 + (lane & 15)) * 64 + ks * 32 + (lane >> 4) * 8];
      acc = mfma16(qf[ks], kf, acc);
    }
    int m = j * 16 + (lane & 15);
#pragma unroll
    for (int jr = 0; jr < 4; jr++){
      float v = (m < NSEQ) ? acc[jr] * lscale : -1e30f;
      S[r0 + (lane >> 4) * 4 + jr][m] = v;
    }
  }
  __syncthreads();
  {
    int row = tid >> 2, sub = tid & 3;
    float mx = -1e38f;
    for (int c2 = sub; c2 < NPAD; c2 += 4) mx = fmaxf(mx, S[row][c2]);
    mx = fmaxf(mx, __shfl_xor(mx, 1)); mx = fmaxf(mx, __shfl_xor(mx, 2));
    float sum = 0.f;
    for (int c2 = sub; c2 < NPAD; c2 += 4){
      float p = expf(S[row][c2] - mx);
      S[row][c2] = p; sum += p;
    }
    sum += __shfl_xor(sum, 1); sum += __shfl_xor(sum, 2);
    if (sub == 0) rsum[row] = sum;
  }
  __syncthreads();
  f32x4 oacc[4];
#pragma unroll
  for (int n = 0; n < 4; n++) oacc[n] = zero;
  for (int ks = 0; ks < 19; ks++){
    int prow = r0 + (lane & 15);
    int kcol = ks * 32 + (lane >> 4) * 8;
    f32x4 p0 = *(const f32x4*)&S[prow][kcol];
    f32x4 p1 = *(const f32x4*)&S[prow][kcol + 4];
    u16x8 ph, pl;
#pragma unroll
    for (int e = 0; e < 4; e++){
      float p = p0[e]; u16 hh = f2bf(p); ph[e] = hh; pl[e] = f2bf(p - bf2f(hh));
      float p2 = p1[e]; u16 h2 = f2bf(p2); ph[e + 4] = h2; pl[e + 4] = f2bf(p2 - bf2f(h2));
    }
#pragma unroll
    for (int n = 0; n < 4; n++){
      u16x8 vf = *(const u16x8*)&ivp[(size_t)(n * 16 + (lane & 15)) * NPAD + kcol];
      oacc[n] = mfma16(ph, vf, oacc[n]);
      oacc[n] = mfma16(pl, vf, oacc[n]);
    }
  }
  float sv = par[P_PQ + 4];
  float lmn = 1e38f, lmx = -1e38f;
#pragma unroll
  for (int jr = 0; jr < 4; jr++){
    int lr = r0 + (lane >> 4) * 4 + jr;
    int gn = q0 + lr;
    if (gn < NSEQ){
      float sc = sv / rsum[lr];
#pragma unroll
      for (int n = 0; n < 4; n++){
        float vv = oacc[n][jr] * sc;
        out[((size_t)(b * 577 + gn)) * 1024 + h * 64 + n * 16 + (lane & 15)] = vv;
        lmn = fminf(lmn, vv); lmx = fmaxf(lmx, vv);
      }
    }
  }
#pragma unroll
  for (int m2 = 32; m2; m2 >>= 1){ lmn = fminf(lmn, __shfl_xor(lmn, m2)); lmx = fmaxf(lmx, __shfl_xor(lmx, m2)); }
  if (lane == 0){
    atomicMin(&paru[P_OUTMM], ford(lmn));
    atomicMax(&paru[P_OUTMM + 1], ford(lmx));
  }
}

__global__ void k_params_out(unsigned* paru){
  if (threadIdx.x == 0){
    float* par = (float*)paru;
    float mn = unford(paru[P_OUTMM]), mx = unford(paru[P_OUTMM + 1]);
    mn = fminf(mn, 0.f); mx = fmaxf(mx, 0.f);
    float s = fmaxf((mx - mn) / QMAXF, 1e-8f);
    par[P_PO] = s;
    par[P_PO + 1] = rintf(-mn / s);
  }
}

__global__ void k_quant_out(const float* __restrict__ outb, const float* __restrict__ par, u16* __restrict__ io){
  float s = par[P_PO], zp = par[P_PO + 1];
  const int total = M_ROWS * 1024 / 4;
  for (int i = blockIdx.x * blockDim.x + threadIdx.x; i < total; i += gridDim.x * blockDim.x){
    f32x4 v = *(const f32x4*)&outb[(size_t)i * 4];
    u16x4 o;
#pragma unroll
    for (int e = 0; e < 4; e++){
      float q = fminf(fmaxf(rintf(v[e] / s) + zp, 0.f), QMAXF);
      o[e] = f2bf(q - zp);
    }
    *(u16x4*)&io[(size_t)i * 4] = o;
  }
}

__global__ __launch_bounds__(256) void k_gemm_proj(const u16* __restrict__ A, const u16* __restrict__ Bm,
    const float* __restrict__ spw, const float* __restrict__ par, const float* __restrict__ bias,
    float* __restrict__ Cout){
  __shared__ u16 As[128 * 32], Bs[128 * 32];
  int tid = threadIdx.x, lane = tid & 63, w = tid >> 6;
  int mt, nt; tilemap(blockIdx.x, gridDim.x, 8, 29, mt, nt);
  int m0 = mt * 128, n0 = nt * 128;
  int wr = (w >> 1) * 64, wc = (w & 1) * 64;
  f32x4 zero = {0.f, 0.f, 0.f, 0.f};
  f32x4 acc[4][4];
#pragma unroll
  for (int m = 0; m < 4; m++)
#pragma unroll
    for (int n = 0; n < 4; n++) acc[m][n] = zero;
  int kc = (lane & 3) * 8;
  for (int kt = 0; kt < 1024; kt += 32){
    __syncthreads();
#pragma unroll
    for (int i = 0; i < 2; i++){
      int ci = w * 2 + i;
      int r = ci * 16 + (lane >> 2);
      int gra = min(m0 + r, M_ROWS - 1);
      gload_lds16(&A[(size_t)gra * 1024 + kt + kc], &As[ci * 512]);
      gload_lds16(&Bm[(size_t)(n0 + r) * 1024 + kt + kc], &Bs[ci * 512]);
    }
    __syncthreads();
    u16x8 af[4];
#pragma unroll
    for (int m = 0; m < 4; m++)
      af[m] = *(const u16x8*)&As[(wr + m * 16 + (lane & 15)) * 32 + (lane >> 4) * 8];
#pragma unroll
    for (int n = 0; n < 4; n++){
      u16x8 bf = *(const u16x8*)&Bs[(wc + n * 16 + (lane & 15)) * 32 + (lane >> 4) * 8];
#pragma unroll
      for (int m = 0; m < 4; m++) acc[m][n] = mfma16(af[m], bf, acc[m][n]);
    }
  }
  float so = par[P_PO];
#pragma unroll
  for (int n = 0; n < 4; n++){
    int col = n0 + wc + n * 16 + (lane & 15);
    float sc = so * spw[col], bv = bias[col];
#pragma unroll
    for (int m = 0; m < 4; m++){
      int rb = m0 + wr + m * 16 + (lane >> 4) * 4;
#pragma unroll
      for (int j = 0; j < 4; j++){
        int row = rb + j;
        if (row < M_ROWS) Cout[(size_t)row * 1024 + col] = acc[m][n][j] * sc + bv;
      }
    }
  }
}

// ---------------- launcher ----------------
extern "C" void kernel_launch(void* const* d_in, const int* in_sizes, int n_in,
                              void* d_out, int out_size, void* d_ws, size_t ws_size,
                              hipStream_t stream){
  (void)in_sizes; (void)n_in; (void)out_size;
  if (ws_size < WS_NEED) return;  // fail validation cleanly instead of faulting
  const float* x      = (const float*)d_in[0];
  const float* qkv_w  = (const float*)d_in[1];
  const float* qkv_b  = (const float*)d_in[2];
  const float* proj_w = (const float*)d_in[3];
  const float* proj_b = (const float*)d_in[4];
  char* ws = (char*)d_ws;
  u16*   ix   = (u16*)(ws + OFF_IX);
  u16*   Bh   = (u16*)(ws + OFF_BH);
  u16*   Bl   = (u16*)(ws + OFF_BL);
  u16*   ik   = (u16*)(ws + OFF_IK);
  u16*   io   = (u16*)(ws + OFF_IO);
  float* f32b = (float*)(ws + OFF_F32);   // vbuf, then kbuf
  u16*   iq   = (u16*)(ws + OFF_IQ);
  u16*   ivT  = (u16*)(ws + OFF_IVT);
  u16*   ipw  = (u16*)(ws + OFF_IPW);
  unsigned* paru = (unsigned*)(ws + OFF_PAR);
  float* parf = (float*)paru;
  float* qbuf = (float*)d_out;            // q fp32, later attn-out fp32

  k_init<<<1, 256, 0, stream>>>(paru);
  k_minmax_x<<<128, 256, 0, stream>>>(x, paru);
  k_params_x<<<4, 256, 0, stream>>>(paru);
  k_quant_x<<<1024, 256, 0, stream>>>(x, parf, ix);
  k_quant_wqkv<<<768, 256, 0, stream>>>(qkv_w, parf, parf + P_SWQ, Bh, Bl);
  k_quant_wproj<<<256, 256, 0, stream>>>(proj_w, parf + P_SPW, ipw);
  // V pass: cols 2048..3071 -> f32b (vbuf)
  k_gemm_qkvpart<<<1160, 256, 0, stream>>>(ix, Bh, Bl, parf + P_SWQ, qkv_b, 2048, 8, f32b, f32b, 2, paru);
  k_params_v<<<1, 64, 0, stream>>>(paru);
  k_quant_v<<<512, 256, 0, stream>>>(f32b, parf, ivT);          // vbuf dead after this
  // QK pass: cols 0..2047 -> q in d_out, k in f32b (kbuf)
  k_gemm_qkvpart<<<2320, 256, 0, stream>>>(ix, Bh, Bl, parf + P_SWQ, qkv_b, 0, 16, qbuf, f32b, 0, paru);
  k_params_qk<<<1, 64, 0, stream>>>(paru);
  k_quant_nd<<<512, 256, 0, stream>>>(f32b, parf, 2, ik);       // kbuf dead after this
  k_quant_nd<<<512, 256, 0, stream>>>(qbuf, parf, 0, iq);       // qbuf (d_out) dead after this
  k_attn<<<9728, 128, 0, stream>>>(iq, ik, ivT, parf, (float*)d_out, paru);
  k_params_out<<<1, 64, 0, stream>>>(paru);
  k_quant_out<<<1024, 256, 0, stream>>>((float*)d_out, parf, io);
  k_gemm_proj<<<1160, 256, 0, stream>>>(io, ipw, parf + P_SPW, parf, proj_b, (float*)d_out);
}

// Round 6
// 1237.031 us; speedup vs baseline: 1.4096x; 1.4096x over previous
//
#include <hip/hip_runtime.h>

typedef unsigned short u16;
typedef float f32x4 __attribute__((ext_vector_type(4)));
typedef u16 u16x8 __attribute__((ext_vector_type(8)));
typedef u16 u16x4 __attribute__((ext_vector_type(4)));
typedef __bf16 bf16x8 __attribute__((ext_vector_type(8)));

#define M_ROWS 18464
#define NSEQ   577
#define NPAD   608
#define QMAXF  255.0f

// ---------------- workspace layout (bytes), peak ~160 MiB ----------------
static constexpr size_t OFF_IX  = 0;                    // 37,814,272
static constexpr size_t OFF_BH  = 37814272;             //  6,291,456
static constexpr size_t OFF_BL  = 44105728;             //  6,291,456 (end 50,397,184)
static constexpr size_t OFF_IK  = 0;                    // 39,845,888
static constexpr size_t OFF_IO  = 0;                    // 37,814,272
static constexpr size_t OFF_F32 = 50397184;             // 75,628,544 (vbuf, then kbuf)
static constexpr size_t OFF_IQ  = 50397184;             // 39,845,888
static constexpr size_t OFF_IVT = 126025728;            // 39,845,888
static constexpr size_t OFF_IPW = 165871616;            //  2,097,152
static constexpr size_t OFF_PAR = 167968768;            // ~33 KB params
static constexpr size_t WS_NEED = 168100000;

// param element indices (within par area)
#define P_XMN   0      /* 1024 */
#define P_XMX   1024   /* 1024 */
#define P_SX    2048   /* 1024 */
#define P_ZPX   3072   /* 1024 */
#define P_SWQ   4096   /* 3072 */
#define P_SPW   7168   /* 1024 */
#define P_QKVMM 8192   /* 6: q mn/mx, k mn/mx, v mn/mx */
#define P_OUTMM 8198   /* 2 */
#define P_PQ    8200   /* 7: sq,zpq,sk,zpk,sv,zpv,lscale */
#define P_PO    8208   /* 2: so,zpo */

// ---------------- small helpers ----------------
__device__ __forceinline__ u16 f2bf(float f){
  unsigned u = __float_as_uint(f);
  unsigned r = u + 0x7fffu + ((u >> 16) & 1u);
  return (u16)(r >> 16);
}
__device__ __forceinline__ float bf2f(u16 h){ return __uint_as_float(((unsigned)h) << 16); }

__device__ __forceinline__ unsigned ford(float f){
  unsigned u = __float_as_uint(f);
  return (u & 0x80000000u) ? ~u : (u | 0x80000000u);
}
__device__ __forceinline__ float unford(unsigned u){
  return (u & 0x80000000u) ? __uint_as_float(u & 0x7fffffffu) : __uint_as_float(~u);
}

__device__ __forceinline__ f32x4 mfma16(u16x8 a, u16x8 b, f32x4 c){
  return __builtin_amdgcn_mfma_f32_16x16x32_bf16(
      __builtin_bit_cast(bf16x8, a), __builtin_bit_cast(bf16x8, b), c, 0, 0, 0);
}

__device__ __forceinline__ void gload_lds16(const void* g, void* l){
  __builtin_amdgcn_global_load_lds((const __attribute__((address_space(1))) unsigned int*)g,
                                   (__attribute__((address_space(3))) unsigned int*)l,
                                   16, 0, 0);
}

// grouped + XCD-bijective tile mapping (requires nwg%8==0, MT%GM==0)
__device__ __forceinline__ void tilemap(int id, int nwg, int NT, int GM, int& mt, int& nt){
  int q = nwg >> 3;
  int swz = (id & 7) * q + (id >> 3);
  int gsz = GM * NT;
  int g = swz / gsz, r = swz % gsz;
  mt = g * GM + (r % GM);
  nt = r / GM;
}

// ---------------- kernels ----------------
__global__ void k_init(unsigned* par){
  int t = threadIdx.x;
  for (int i = t; i < 1024; i += 256){ par[P_XMN + i] = 0xFFFFFFFFu; par[P_XMX + i] = 0u; }
  if (t < 6) par[P_QKVMM + t] = (t & 1) ? 0u : 0xFFFFFFFFu;
  if (t < 2) par[P_OUTMM + t] = (t & 1) ? 0u : 0xFFFFFFFFu;
}

__global__ void k_minmax_x(const float* __restrict__ x, unsigned* par){
  int t = threadIdx.x;
  int r0 = blockIdx.x * 145;
  int r1 = min(r0 + 145, M_ROWS);
  float mn[4], mx[4];
#pragma unroll
  for (int e = 0; e < 4; e++){ mn[e] = 1e38f; mx[e] = -1e38f; }
  for (int r = r0; r < r1; r++){
    f32x4 v = *(const f32x4*)&x[(size_t)r * 1024 + t * 4];
#pragma unroll
    for (int e = 0; e < 4; e++){ mn[e] = fminf(mn[e], v[e]); mx[e] = fmaxf(mx[e], v[e]); }
  }
#pragma unroll
  for (int e = 0; e < 4; e++){
    atomicMin(&par[P_XMN + t * 4 + e], ford(mn[e]));
    atomicMax(&par[P_XMX + t * 4 + e], ford(mx[e]));
  }
}

__global__ void k_params_x(unsigned* paru){
  float* par = (float*)paru;
  int c = blockIdx.x * 256 + threadIdx.x;
  if (c < 1024){
    float mn = unford(paru[P_XMN + c]);
    float mx = unford(paru[P_XMX + c]);
    mn = fminf(mn, 0.f); mx = fmaxf(mx, 0.f);
    float s = fmaxf((mx - mn) / QMAXF, 1e-8f);
    par[P_SX + c] = s;
    par[P_ZPX + c] = rintf(-mn / s);
  }
}

__global__ void k_quant_x(const float* __restrict__ x, const float* __restrict__ par, u16* __restrict__ ix){
  const int total = M_ROWS * 1024 / 4;
  for (int i = blockIdx.x * blockDim.x + threadIdx.x; i < total; i += gridDim.x * blockDim.x){
    f32x4 v  = *(const f32x4*)&x[(size_t)i * 4];
    int c = (i * 4) & 1023;
    f32x4 s  = *(const f32x4*)&par[P_SX + c];
    f32x4 zp = *(const f32x4*)&par[P_ZPX + c];
    u16x4 o;
#pragma unroll
    for (int e = 0; e < 4; e++){
      float q = fminf(fmaxf(rintf(v[e] / s[e]) + zp[e], 0.f), QMAXF);
      o[e] = f2bf(q - zp[e]);
    }
    *(u16x4*)&ix[(size_t)i * 4] = o;
  }
}

// per-out-channel weight quant for qkv_w; Bh/Bl = bf16 split of sx_c * (qw - zpw)
__global__ void k_quant_wqkv(const float* __restrict__ w, const float* __restrict__ par,
                             float* __restrict__ swq, u16* __restrict__ Bh, u16* __restrict__ Bl){
  int lane = threadIdx.x & 63, wv = threadIdx.x >> 6;
  int row = blockIdx.x * 4 + wv;
  const float* wr = w + (size_t)row * 1024;
  f32x4 v[4];
  float mn = 1e38f, mx = -1e38f;
#pragma unroll
  for (int j = 0; j < 4; j++){
    v[j] = *(const f32x4*)&wr[j * 256 + lane * 4];
#pragma unroll
    for (int e = 0; e < 4; e++){ mn = fminf(mn, v[j][e]); mx = fmaxf(mx, v[j][e]); }
  }
#pragma unroll
  for (int m = 1; m < 64; m <<= 1){ mn = fminf(mn, __shfl_xor(mn, m)); mx = fmaxf(mx, __shfl_xor(mx, m)); }
  mn = fminf(mn, 0.f); mx = fmaxf(mx, 0.f);
  float s = fmaxf((mx - mn) / QMAXF, 1e-8f);
  float zp = rintf(-mn / s);
  if (lane == 0) swq[row] = s;
#pragma unroll
  for (int j = 0; j < 4; j++){
    int c = j * 256 + lane * 4;
    f32x4 sx = *(const f32x4*)&par[P_SX + c];
    u16x4 oh, ol;
#pragma unroll
    for (int e = 0; e < 4; e++){
      float q = fminf(fmaxf(rintf(v[j][e] / s) + zp, 0.f), QMAXF);
      float bp = sx[e] * (q - zp);
      u16 hh = f2bf(bp);
      oh[e] = hh;
      ol[e] = f2bf(bp - bf2f(hh));
    }
    *(u16x4*)&Bh[(size_t)row * 1024 + c] = oh;
    *(u16x4*)&Bl[(size_t)row * 1024 + c] = ol;
  }
}

// proj weight: exact int bf16, scale factored to epilogue
__global__ void k_quant_wproj(const float* __restrict__ w, float* __restrict__ spw, u16* __restrict__ ipw){
  int lane = threadIdx.x & 63, wv = threadIdx.x >> 6;
  int row = blockIdx.x * 4 + wv;
  const float* wr = w + (size_t)row * 1024;
  f32x4 v[4];
  float mn = 1e38f, mx = -1e38f;
#pragma unroll
  for (int j = 0; j < 4; j++){
    v[j] = *(const f32x4*)&wr[j * 256 + lane * 4];
#pragma unroll
    for (int e = 0; e < 4; e++){ mn = fminf(mn, v[j][e]); mx = fmaxf(mx, v[j][e]); }
  }
#pragma unroll
  for (int m = 1; m < 64; m <<= 1){ mn = fminf(mn, __shfl_xor(mn, m)); mx = fmaxf(mx, __shfl_xor(mx, m)); }
  mn = fminf(mn, 0.f); mx = fmaxf(mx, 0.f);
  float s = fmaxf((mx - mn) / QMAXF, 1e-8f);
  float zp = rintf(-mn / s);
  if (lane == 0) spw[row] = s;
#pragma unroll
  for (int j = 0; j < 4; j++){
    int c = j * 256 + lane * 4;
    u16x4 o;
#pragma unroll
    for (int e = 0; e < 4; e++){
      float q = fminf(fmaxf(rintf(v[j][e] / s) + zp, 0.f), QMAXF);
      o[e] = f2bf(q - zp);
    }
    *(u16x4*)&ipw[(size_t)row * 1024 + c] = o;
  }
}

// C[:, bcol_off : bcol_off+NT*128] = ix @ (Bh+Bl)^T * swq + bias; per-seg minmax.
__global__ __launch_bounds__(256) void k_gemm_qkvpart(const u16* __restrict__ A,
    const u16* __restrict__ Bh, const u16* __restrict__ Bl, const float* __restrict__ swq,
    const float* __restrict__ bias, int bcol_off, int NT, float* dst0, float* dst1,
    int seg0, unsigned* paru){
  __shared__ u16 As[128 * 32], Bhs[128 * 32], Bls[128 * 32];
  int tid = threadIdx.x, lane = tid & 63, w = tid >> 6;
  int mt, nt; tilemap(blockIdx.x, gridDim.x, NT, 29, mt, nt);
  int m0 = mt * 128, n0 = nt * 128;
  int wr = (w >> 1) * 64, wc = (w & 1) * 64;
  f32x4 zero = {0.f, 0.f, 0.f, 0.f};
  f32x4 acc[4][4];
#pragma unroll
  for (int m = 0; m < 4; m++)
#pragma unroll
    for (int n = 0; n < 4; n++) acc[m][n] = zero;
  int kc = (lane & 3) * 8;
  for (int kt = 0; kt < 1024; kt += 32){
    __syncthreads();
#pragma unroll
    for (int i = 0; i < 2; i++){
      int ci = w * 2 + i;
      int r = ci * 16 + (lane >> 2);
      int gra = min(m0 + r, M_ROWS - 1);
      gload_lds16(&A[(size_t)gra * 1024 + kt + kc], &As[ci * 512]);
      size_t grb = (size_t)(bcol_off + n0 + r) * 1024 + kt + kc;
      gload_lds16(&Bh[grb], &Bhs[ci * 512]);
      gload_lds16(&Bl[grb], &Bls[ci * 512]);
    }
    __syncthreads();
    u16x8 af[4];
#pragma unroll
    for (int m = 0; m < 4; m++)
      af[m] = *(const u16x8*)&As[(wr + m * 16 + (lane & 15)) * 32 + (lane >> 4) * 8];
#pragma unroll
    for (int n = 0; n < 4; n++){
      u16x8 bh = *(const u16x8*)&Bhs[(wc + n * 16 + (lane & 15)) * 32 + (lane >> 4) * 8];
      u16x8 bl = *(const u16x8*)&Bls[(wc + n * 16 + (lane & 15)) * 32 + (lane >> 4) * 8];
#pragma unroll
      for (int m = 0; m < 4; m++){
        acc[m][n] = mfma16(af[m], bh, acc[m][n]);
        acc[m][n] = mfma16(af[m], bl, acc[m][n]);
      }
    }
  }
  float lmn = 1e38f, lmx = -1e38f;
#pragma unroll
  for (int n = 0; n < 4; n++){
    int cl = n0 + wc + n * 16 + (lane & 15);
    float sw = swq[bcol_off + cl], bv = bias[bcol_off + cl];
    float* dst = (cl < 1024) ? dst0 : dst1;
    int cs = cl & 1023;
#pragma unroll
    for (int m = 0; m < 4; m++){
      int rb = m0 + wr + m * 16 + (lane >> 4) * 4;
#pragma unroll
      for (int j = 0; j < 4; j++){
        int row = rb + j;
        if (row < M_ROWS){
          float vv = acc[m][n][j] * sw + bv;
          dst[(size_t)row * 1024 + cs] = vv;
          lmn = fminf(lmn, vv); lmx = fmaxf(lmx, vv);
        }
      }
    }
  }
  int seg = seg0 + (n0 >> 10);
#pragma unroll
  for (int m = 32; m; m >>= 1){ lmn = fminf(lmn, __shfl_xor(lmn, m)); lmx = fmaxf(lmx, __shfl_xor(lmx, m)); }
  if (lane == 0){
    atomicMin(&paru[P_QKVMM + seg * 2], ford(lmn));
    atomicMax(&paru[P_QKVMM + seg * 2 + 1], ford(lmx));
  }
}

__global__ void k_params_v(unsigned* paru){
  if (threadIdx.x == 0){
    float* par = (float*)paru;
    float mn = unford(paru[P_QKVMM + 4]);
    float mx = unford(paru[P_QKVMM + 5]);
    mn = fminf(mn, 0.f); mx = fmaxf(mx, 0.f);
    float s = fmaxf((mx - mn) / QMAXF, 1e-8f);
    par[P_PQ + 4] = s;
    par[P_PQ + 5] = rintf(-mn / s);
  }
}

__global__ void k_params_qk(unsigned* paru){
  if (threadIdx.x == 0){
    float* par = (float*)paru;
    float sv[2];
    for (int t = 0; t < 2; t++){
      float mn = unford(paru[P_QKVMM + t * 2]);
      float mx = unford(paru[P_QKVMM + t * 2 + 1]);
      mn = fminf(mn, 0.f); mx = fmaxf(mx, 0.f);
      float s = fmaxf((mx - mn) / QMAXF, 1e-8f);
      sv[t] = s;
      par[P_PQ + t * 2] = s;
      par[P_PQ + t * 2 + 1] = rintf(-mn / s);
    }
    par[P_PQ + 6] = sv[0] * sv[1] * 0.125f;
  }
}

// quantize v (per-tensor) + transpose head-block to [64][NPAD]
__global__ void k_quant_v(const float* __restrict__ vbuf, const float* __restrict__ par,
                          u16* __restrict__ ivT){
  int bh = blockIdx.x, b = bh >> 4, h = bh & 15;
  int tid = threadIdx.x;
  __shared__ unsigned vtu[64][37];
  float s = par[P_PQ + 4], zp = par[P_PQ + 5];
  const float* vsrc = vbuf + (size_t)b * 577 * 1024 + h * 64;
  u16* vdst = ivT + (size_t)bh * 64 * NPAD;
  for (int c0 = 0; c0 < 10; c0++){
    int n0 = c0 * 64;
    __syncthreads();
    for (int idx = tid; idx < 64 * 32; idx += 256){
      int d = idx & 63, p = idx >> 6;
      int n1 = n0 + 2 * p, n2 = n1 + 1;
      float v1 = 0.f, v2 = 0.f;
      if (n1 < NSEQ){
        float xx = vsrc[(size_t)n1 * 1024 + d];
        float q = fminf(fmaxf(rintf(xx / s) + zp, 0.f), QMAXF);
        v1 = q - zp;
      }
      if (n2 < NSEQ){
        float xx = vsrc[(size_t)n2 * 1024 + d];
        float q = fminf(fmaxf(rintf(xx / s) + zp, 0.f), QMAXF);
        v2 = q - zp;
      }
      vtu[d][p] = (unsigned)f2bf(v1) | ((unsigned)f2bf(v2) << 16);
    }
    __syncthreads();
    for (int idx = tid; idx < 64 * 32; idx += 256){
      int p = idx & 31, d = idx >> 5;
      int n = n0 + 2 * p;
      if (n < NPAD) *(unsigned*)&vdst[(size_t)d * NPAD + n] = vtu[d][p];
    }
  }
}

// quantize q or k (per-tensor) into [bh][NPAD][64] int-bf16
__global__ void k_quant_nd(const float* __restrict__ buf, const float* __restrict__ par,
                           int pidx, u16* __restrict__ dst){
  int bh = blockIdx.x, b = bh >> 4, h = bh & 15;
  int tid = threadIdx.x;
  float s = par[P_PQ + pidx], zp = par[P_PQ + pidx + 1];
  u16* d0p = dst + (size_t)bh * NPAD * 64;
  for (int idx = tid; idx < NPAD * 16; idx += 256){
    int n = idx >> 4, d0 = (idx & 15) * 4;
    u16x4 o = {0, 0, 0, 0};
    if (n < NSEQ){
      f32x4 v = *(const f32x4*)&buf[((size_t)(b * 577 + n)) * 1024 + h * 64 + d0];
#pragma unroll
      for (int e = 0; e < 4; e++){
        float q = fminf(fmaxf(rintf(v[e] / s) + zp, 0.f), QMAXF);
        o[e] = f2bf(q - zp);
      }
    }
    *(u16x4*)&d0p[n * 64 + d0] = o;
  }
}

// flash-style attention: 4 waves x 32 q-rows, online softmax in registers,
// K/V direct from global (L2-resident per head), P via small per-wave LDS.
__global__ __launch_bounds__(256) void k_attn(const u16* __restrict__ iq, const u16* __restrict__ ik,
    const u16* __restrict__ ivT, const float* __restrict__ par, float* __restrict__ out, unsigned* paru){
  __shared__ __attribute__((aligned(16))) u16 plds[4][2][2][16][40]; // [wave][qgrp][h/l][qrow%16][k%32 pad40]
  int tile = blockIdx.x;
  int xcd = tile & 7, slot = tile >> 3;
  int bh = (slot / 5) * 8 + xcd, qt = slot % 5;   // head's 5 blocks share an XCD
  int b = bh >> 4, h = bh & 15;
  int tid = threadIdx.x, lane = tid & 63, w = tid >> 6;
  int lo = lane & 15, hi = lane >> 4;
  int q0 = qt * 128 + w * 32;
  const u16* iqp = iq + (size_t)bh * NPAD * 64;
  const u16* ikp = ik + (size_t)bh * NPAD * 64;
  const u16* ivp = ivT + (size_t)bh * 64 * NPAD;
  float lscale = par[P_PQ + 6];
  u16x8 qf[2][2];
#pragma unroll
  for (int g = 0; g < 2; g++){
    int qr = min(q0 + g * 16 + lo, NPAD - 1);   // clamp padded rows (garbage ok)
#pragma unroll
    for (int ks = 0; ks < 2; ks++)
      qf[g][ks] = *(const u16x8*)&iqp[(size_t)qr * 64 + ks * 32 + hi * 8];
  }
  f32x4 zero = {0.f, 0.f, 0.f, 0.f};
  f32x4 oacc[2][4];
  float mrow[2][4], lrow[2][4];
#pragma unroll
  for (int g = 0; g < 2; g++){
#pragma unroll
    for (int n = 0; n < 4; n++) oacc[g][n] = zero;
#pragma unroll
    for (int j = 0; j < 4; j++){ mrow[g][j] = -1e30f; lrow[g][j] = 0.f; }
  }
  for (int kt = 0; kt < 19; kt++){
    int k0 = kt * 32;
    u16x8 vf[4];
#pragma unroll
    for (int n = 0; n < 4; n++)
      vf[n] = *(const u16x8*)&ivp[(size_t)(n * 16 + lo) * NPAD + k0 + hi * 8];
    u16x8 kf[2][2];
#pragma unroll
    for (int t = 0; t < 2; t++)
#pragma unroll
      for (int ks = 0; ks < 2; ks++)
        kf[t][ks] = *(const u16x8*)&ikp[(size_t)(k0 + t * 16 + lo) * 64 + ks * 32 + hi * 8];
    f32x4 acc[2][2];
#pragma unroll
    for (int g = 0; g < 2; g++)
#pragma unroll
      for (int t = 0; t < 2; t++){
        f32x4 a = mfma16(qf[g][0], kf[t][0], zero);
        acc[g][t] = mfma16(qf[g][1], kf[t][1], a);
      }
    int kg0 = k0 + lo;
#pragma unroll
    for (int g = 0; g < 2; g++){
#pragma unroll
      for (int j = 0; j < 4; j++){
        float s0 = (kg0 < NSEQ) ? acc[g][0][j] * lscale : -1e30f;
        float s1 = (kg0 + 16 < NSEQ) ? acc[g][1][j] * lscale : -1e30f;
        float mx = fmaxf(s0, s1);
#pragma unroll
        for (int mk = 1; mk < 16; mk <<= 1) mx = fmaxf(mx, __shfl_xor(mx, mk));
        float mnew = fmaxf(mrow[g][j], mx);
        float sf = __expf(mrow[g][j] - mnew);   // exactly 1.0 when max unchanged
        mrow[g][j] = mnew;
        float p0 = __expf(s0 - mnew);
        float p1 = __expf(s1 - mnew);
        float ps = p0 + p1;
#pragma unroll
        for (int mk = 1; mk < 16; mk <<= 1) ps += __shfl_xor(ps, mk);
        lrow[g][j] = lrow[g][j] * sf + ps;
#pragma unroll
        for (int n = 0; n < 4; n++) oacc[g][n][j] *= sf;
        int row = hi * 4 + j;
        u16 h0 = f2bf(p0), h1 = f2bf(p1);
        plds[w][g][0][row][lo]      = h0;
        plds[w][g][0][row][lo + 16] = h1;
        plds[w][g][1][row][lo]      = f2bf(p0 - bf2f(h0));
        plds[w][g][1][row][lo + 16] = f2bf(p1 - bf2f(h1));
      }
    }
#pragma unroll
    for (int g = 0; g < 2; g++){
      u16x8 pah = *(const u16x8*)&plds[w][g][0][lo][hi * 8];
      u16x8 pal = *(const u16x8*)&plds[w][g][1][lo][hi * 8];
#pragma unroll
      for (int n = 0; n < 4; n++){
        oacc[g][n] = mfma16(pah, vf[n], oacc[g][n]);
        oacc[g][n] = mfma16(pal, vf[n], oacc[g][n]);
      }
    }
  }
  float sv = par[P_PQ + 4];
  float lmn = 1e38f, lmx = -1e38f;
#pragma unroll
  for (int g = 0; g < 2; g++){
#pragma unroll
    for (int j = 0; j < 4; j++){
      int gn = q0 + g * 16 + hi * 4 + j;
      if (gn < NSEQ){
        float sc = sv / lrow[g][j];
#pragma unroll
        for (int n = 0; n < 4; n++){
          float vv = oacc[g][n][j] * sc;
          out[((size_t)(b * 577 + gn)) * 1024 + h * 64 + n * 16 + lo] = vv;
          lmn = fminf(lmn, vv); lmx = fmaxf(lmx, vv);
        }
      }
    }
  }
#pragma unroll
  for (int m2 = 32; m2; m2 >>= 1){ lmn = fminf(lmn, __shfl_xor(lmn, m2)); lmx = fmaxf(lmx, __shfl_xor(lmx, m2)); }
  if (lane == 0){
    atomicMin(&paru[P_OUTMM], ford(lmn));
    atomicMax(&paru[P_OUTMM + 1], ford(lmx));
  }
}

__global__ void k_params_out(unsigned* paru){
  if (threadIdx.x == 0){
    float* par = (float*)paru;
    float mn = unford(paru[P_OUTMM]), mx = unford(paru[P_OUTMM + 1]);
    mn = fminf(mn, 0.f); mx = fmaxf(mx, 0.f);
    float s = fmaxf((mx - mn) / QMAXF, 1e-8f);
    par[P_PO] = s;
    par[P_PO + 1] = rintf(-mn / s);
  }
}

__global__ void k_quant_out(const float* __restrict__ outb, const float* __restrict__ par, u16* __restrict__ io){
  float s = par[P_PO], zp = par[P_PO + 1];
  const int total = M_ROWS * 1024 / 4;
  for (int i = blockIdx.x * blockDim.x + threadIdx.x; i < total; i += gridDim.x * blockDim.x){
    f32x4 v = *(const f32x4*)&outb[(size_t)i * 4];
    u16x4 o;
#pragma unroll
    for (int e = 0; e < 4; e++){
      float q = fminf(fmaxf(rintf(v[e] / s) + zp, 0.f), QMAXF);
      o[e] = f2bf(q - zp);
    }
    *(u16x4*)&io[(size_t)i * 4] = o;
  }
}

__global__ __launch_bounds__(256) void k_gemm_proj(const u16* __restrict__ A, const u16* __restrict__ Bm,
    const float* __restrict__ spw, const float* __restrict__ par, const float* __restrict__ bias,
    float* __restrict__ Cout){
  __shared__ u16 As[128 * 32], Bs[128 * 32];
  int tid = threadIdx.x, lane = tid & 63, w = tid >> 6;
  int mt, nt; tilemap(blockIdx.x, gridDim.x, 8, 29, mt, nt);
  int m0 = mt * 128, n0 = nt * 128;
  int wr = (w >> 1) * 64, wc = (w & 1) * 64;
  f32x4 zero = {0.f, 0.f, 0.f, 0.f};
  f32x4 acc[4][4];
#pragma unroll
  for (int m = 0; m < 4; m++)
#pragma unroll
    for (int n = 0; n < 4; n++) acc[m][n] = zero;
  int kc = (lane & 3) * 8;
  for (int kt = 0; kt < 1024; kt += 32){
    __syncthreads();
#pragma unroll
    for (int i = 0; i < 2; i++){
      int ci = w * 2 + i;
      int r = ci * 16 + (lane >> 2);
      int gra = min(m0 + r, M_ROWS - 1);
      gload_lds16(&A[(size_t)gra * 1024 + kt + kc], &As[ci * 512]);
      gload_lds16(&Bm[(size_t)(n0 + r) * 1024 + kt + kc], &Bs[ci * 512]);
    }
    __syncthreads();
    u16x8 af[4];
#pragma unroll
    for (int m = 0; m < 4; m++)
      af[m] = *(const u16x8*)&As[(wr + m * 16 + (lane & 15)) * 32 + (lane >> 4) * 8];
#pragma unroll
    for (int n = 0; n < 4; n++){
      u16x8 bf = *(const u16x8*)&Bs[(wc + n * 16 + (lane & 15)) * 32 + (lane >> 4) * 8];
#pragma unroll
      for (int m = 0; m < 4; m++) acc[m][n] = mfma16(af[m], bf, acc[m][n]);
    }
  }
  float so = par[P_PO];
#pragma unroll
  for (int n = 0; n < 4; n++){
    int col = n0 + wc + n * 16 + (lane & 15);
    float sc = so * spw[col], bv = bias[col];
#pragma unroll
    for (int m = 0; m < 4; m++){
      int rb = m0 + wr + m * 16 + (lane >> 4) * 4;
#pragma unroll
      for (int j = 0; j < 4; j++){
        int row = rb + j;
        if (row < M_ROWS) Cout[(size_t)row * 1024 + col] = acc[m][n][j] * sc + bv;
      }
    }
  }
}

// ---------------- launcher ----------------
extern "C" void kernel_launch(void* const* d_in, const int* in_sizes, int n_in,
                              void* d_out, int out_size, void* d_ws, size_t ws_size,
                              hipStream_t stream){
  (void)in_sizes; (void)n_in; (void)out_size;
  if (ws_size < WS_NEED) return;  // fail validation cleanly instead of faulting
  const float* x      = (const float*)d_in[0];
  const float* qkv_w  = (const float*)d_in[1];
  const float* qkv_b  = (const float*)d_in[2];
  const float* proj_w = (const float*)d_in[3];
  const float* proj_b = (const float*)d_in[4];
  char* ws = (char*)d_ws;
  u16*   ix   = (u16*)(ws + OFF_IX);
  u16*   Bh   = (u16*)(ws + OFF_BH);
  u16*   Bl   = (u16*)(ws + OFF_BL);
  u16*   ik   = (u16*)(ws + OFF_IK);
  u16*   io   = (u16*)(ws + OFF_IO);
  float* f32b = (float*)(ws + OFF_F32);   // vbuf, then kbuf
  u16*   iq   = (u16*)(ws + OFF_IQ);
  u16*   ivT  = (u16*)(ws + OFF_IVT);
  u16*   ipw  = (u16*)(ws + OFF_IPW);
  unsigned* paru = (unsigned*)(ws + OFF_PAR);
  float* parf = (float*)paru;
  float* qbuf = (float*)d_out;            // q fp32, later attn-out fp32

  k_init<<<1, 256, 0, stream>>>(paru);
  k_minmax_x<<<128, 256, 0, stream>>>(x, paru);
  k_params_x<<<4, 256, 0, stream>>>(paru);
  k_quant_x<<<1024, 256, 0, stream>>>(x, parf, ix);
  k_quant_wqkv<<<768, 256, 0, stream>>>(qkv_w, parf, parf + P_SWQ, Bh, Bl);
  k_quant_wproj<<<256, 256, 0, stream>>>(proj_w, parf + P_SPW, ipw);
  // V pass: cols 2048..3071 -> f32b (vbuf)
  k_gemm_qkvpart<<<1160, 256, 0, stream>>>(ix, Bh, Bl, parf + P_SWQ, qkv_b, 2048, 8, f32b, f32b, 2, paru);
  k_params_v<<<1, 64, 0, stream>>>(paru);
  k_quant_v<<<512, 256, 0, stream>>>(f32b, parf, ivT);          // vbuf dead after this
  // QK pass: cols 0..2047 -> q in d_out, k in f32b (kbuf)
  k_gemm_qkvpart<<<2320, 256, 0, stream>>>(ix, Bh, Bl, parf + P_SWQ, qkv_b, 0, 16, qbuf, f32b, 0, paru);
  k_params_qk<<<1, 64, 0, stream>>>(paru);
  k_quant_nd<<<512, 256, 0, stream>>>(f32b, parf, 2, ik);       // kbuf dead after this
  k_quant_nd<<<512, 256, 0, stream>>>(qbuf, parf, 0, iq);       // qbuf (d_out) dead after this
  k_attn<<<2560, 256, 0, stream>>>(iq, ik, ivT, parf, (float*)d_out, paru);
  k_params_out<<<1, 64, 0, stream>>>(paru);
  k_quant_out<<<1024, 256, 0, stream>>>((float*)d_out, parf, io);
  k_gemm_proj<<<1160, 256, 0, stream>>>(io, ipw, parf + P_SPW, parf, proj_b, (float*)d_out);
}